// Round 2
// baseline (8515.701 us; speedup 1.0000x reference)
//
#include <hip/hip_runtime.h>
#include <hip/hip_bf16.h>

#define B_ 4
#define S_ 1024
#define E_ 1280
#define H_ 16
#define D_ 80
#define M_ (B_*S_)   // 4096

typedef __hip_bfloat16 bf16;

__device__ __forceinline__ float b2f(bf16 x){ return __bfloat162float(x); }
__device__ __forceinline__ bf16  f2b(float x){ return __float2bfloat16(x); }

__device__ __forceinline__ float ldf(const float* p){ return *p; }
__device__ __forceinline__ float ldf(const bf16*  p){ return b2f(*p); }
__device__ __forceinline__ void  stf(float* p, float v){ *p = v; }
__device__ __forceinline__ void  stf(bf16*  p, float v){ *p = f2b(v); }

// C[m,n] = sum_k A[m,k]*W[n,k] + bias[n]   (A: MxK TA, W: NxK fp32)
// blockIdx.z selects (W, bias, C) -- does Q,K,V in one launch.
template<typename TA, typename TC>
__global__ __launch_bounds__(256) void gemm_nt_bias(
    const TA* __restrict__ A,
    const float* __restrict__ W0, const float* __restrict__ W1, const float* __restrict__ W2,
    const float* __restrict__ b0, const float* __restrict__ b1, const float* __restrict__ b2,
    TC* __restrict__ C0, TC* __restrict__ C1, TC* __restrict__ C2,
    int K, int N)
{
    const float* W; const float* bias; TC* C;
    if (blockIdx.z == 0)      { W = W0; bias = b0; C = C0; }
    else if (blockIdx.z == 1) { W = W1; bias = b1; C = C1; }
    else                      { W = W2; bias = b2; C = C2; }

    __shared__ float As[64][17];
    __shared__ float Ws[64][17];
    const int tid = threadIdx.x;
    const int tx = tid & 15, ty = tid >> 4;
    const int bm = blockIdx.x * 64, bn = blockIdx.y * 64;

    float acc[4][4] = {};

    for (int k0 = 0; k0 < K; k0 += 16) {
        #pragma unroll
        for (int i = 0; i < 4; i++) {
            int idx = tid + i * 256;
            int r = idx >> 4, c = idx & 15;
            As[r][c] = ldf(&A[(size_t)(bm + r) * K + k0 + c]);
            Ws[r][c] = W[(size_t)(bn + r) * K + k0 + c];
        }
        __syncthreads();
        #pragma unroll
        for (int kk = 0; kk < 16; kk++) {
            float a[4], w[4];
            #pragma unroll
            for (int i = 0; i < 4; i++) a[i] = As[ty*4 + i][kk];
            #pragma unroll
            for (int j = 0; j < 4; j++) w[j] = Ws[tx*4 + j][kk];
            #pragma unroll
            for (int i = 0; i < 4; i++)
                #pragma unroll
                for (int j = 0; j < 4; j++) acc[i][j] += a[i] * w[j];
        }
        __syncthreads();
    }

    #pragma unroll
    for (int i = 0; i < 4; i++) {
        int m = bm + ty*4 + i;
        #pragma unroll
        for (int j = 0; j < 4; j++) {
            int n = bn + tx*4 + j;
            stf(&C[(size_t)m * N + n], acc[i][j] + bias[n]);
        }
    }
}

// In-place RoPE on q and k (bf16 workspace). One thread per (j, j+40) pair.
// cos/sin are (S, 80) fp32 with cos[s][j] == cos[s][j+40].
__global__ void rope_kernel(bf16* __restrict__ q, bf16* __restrict__ k,
                            const float* __restrict__ cosp, const float* __restrict__ sinp)
{
    const int P = B_ * S_ * H_ * 40;   // pairs per tensor
    int t = blockIdx.x * blockDim.x + threadIdx.x;
    if (t >= 2 * P) return;
    bf16* ten = (t < P) ? q : k;
    int r = (t < P) ? t : t - P;
    int j = r % 40;
    int h = (r / 40) % H_;
    int s = (r / (40 * H_)) % S_;
    int b = r / (40 * H_ * S_);
    size_t row = (size_t)(b * S_ + s) * E_;
    int c1 = h * D_ + j, c2 = c1 + 40;
    float cs = cosp[s * D_ + j];
    float sn = sinp[s * D_ + j];
    float q1 = b2f(ten[row + c1]), q2 = b2f(ten[row + c2]);
    ten[row + c1] = f2b(q1 * cs - q2 * sn);   // out[:40] = x1*c - x2*s
    ten[row + c2] = f2b(q2 * cs + q1 * sn);   // out[40:] = x2*c + x1*s
}

// One block per (q-row s, head h, batch b). 256 threads.
// Exact reference masking: score = -1e9 if (!valid_q || !valid_k); softmax over all 1024 keys.
__global__ __launch_bounds__(256) void attn_kernel(
    const bf16* __restrict__ q, const bf16* __restrict__ k, const bf16* __restrict__ v,
    const int* __restrict__ cu, bf16* __restrict__ o)
{
    const int s = blockIdx.x, h = blockIdx.y, b = blockIdx.z;
    const int tid = threadIdx.x;
    __shared__ float qs[D_];
    __shared__ float p[S_];
    __shared__ float red[256];
    __shared__ float op[3][D_];

    const int len = cu[b + 1] - cu[b];
    const bool validq = (s < len);
    const size_t qrow = (size_t)(b * S_ + s) * E_ + (size_t)h * D_;
    if (tid < D_) qs[tid] = b2f(q[qrow + tid]);
    __syncthreads();

    const float scale = 0.11180339887498949f;  // 1/sqrt(80)
    float sc[4];
    float lmax = -1e30f;
    #pragma unroll
    for (int i = 0; i < 4; i++) {
        int kk = tid + i * 256;
        const bf16* kp = k + (size_t)(b * S_ + kk) * E_ + (size_t)h * D_;
        float dot = 0.f;
        for (int d = 0; d < D_; d++) dot += qs[d] * b2f(kp[d]);
        float scv = (validq && kk < len) ? dot * scale : -1e9f;
        sc[i] = scv;
        lmax = fmaxf(lmax, scv);
    }
    red[tid] = lmax; __syncthreads();
    for (int st = 128; st > 0; st >>= 1) {
        if (tid < st) red[tid] = fmaxf(red[tid], red[tid + st]);
        __syncthreads();
    }
    float m = red[0];
    __syncthreads();
    float lsum = 0.f;
    #pragma unroll
    for (int i = 0; i < 4; i++) {
        float e = expf(sc[i] - m);
        p[tid + i * 256] = e;
        lsum += e;
    }
    red[tid] = lsum; __syncthreads();
    for (int st = 128; st > 0; st >>= 1) {
        if (tid < st) red[tid] += red[tid + st];
        __syncthreads();
    }
    const float inv = 1.0f / red[0];

    // PV: 240 threads = 80 dims x 3 k-groups
    if (tid < 240) {
        int g = tid / D_, d = tid - g * D_;
        float acc = 0.f;
        for (int kk = g; kk < S_; kk += 3)
            acc += p[kk] * b2f(v[(size_t)(b * S_ + kk) * E_ + (size_t)h * D_ + d]);
        op[g][d] = acc;
    }
    __syncthreads();
    if (tid < D_) {
        float r = (op[0][tid] + op[1][tid] + op[2][tid]) * inv;
        o[qrow + tid] = f2b(r);
    }
}

extern "C" void kernel_launch(void* const* d_in, const int* in_sizes, int n_in,
                              void* d_out, int out_size, void* d_ws, size_t ws_size,
                              hipStream_t stream)
{
    const float* x    = (const float*)d_in[0];
    const int*   cu   = (const int*)  d_in[1];
    const float* cosp = (const float*)d_in[2];
    const float* sinp = (const float*)d_in[3];
    const float* wq   = (const float*)d_in[4];
    const float* bq   = (const float*)d_in[5];
    const float* wk   = (const float*)d_in[6];
    const float* bk   = (const float*)d_in[7];
    const float* wv   = (const float*)d_in[8];
    const float* bv   = (const float*)d_in[9];
    const float* wo   = (const float*)d_in[10];
    const float* bo   = (const float*)d_in[11];
    float* out = (float*)d_out;

    // workspace (bf16): q, k, v, attn_out -- each 4096*1280 = 10.5 MB, total 42 MB
    bf16* q  = (bf16*)d_ws;
    bf16* kk = q  + (size_t)M_ * E_;
    bf16* vv = kk + (size_t)M_ * E_;
    bf16* ao = vv + (size_t)M_ * E_;

    // 1) QKV projection (bias added, no rope yet): fp32 in -> bf16 ws
    dim3 g1(M_ / 64, E_ / 64, 3);
    gemm_nt_bias<float, bf16><<<g1, 256, 0, stream>>>(
        x, wq, wk, wv, bq, bk, bv, q, kk, vv, E_, E_);

    // 2) RoPE in place on q and k
    int P2 = 2 * B_ * S_ * H_ * 40;
    rope_kernel<<<(P2 + 255) / 256, 256, 0, stream>>>(q, kk, cosp, sinp);

    // 3) attention with varlen masking
    attn_kernel<<<dim3(S_, H_, B_), 256, 0, stream>>>(q, kk, vv, cu, ao);

    // 4) output projection: bf16 ws in -> fp32 out
    dim3 g2(M_ / 64, E_ / 64, 1);
    gemm_nt_bias<bf16, float><<<g2, 256, 0, stream>>>(
        ao, wo, wo, wo, bo, bo, bo, out, out, out, E_, E_);
}

// Round 3
// 1709.012 us; speedup vs baseline: 4.9828x; 4.9828x over previous
//
#include <hip/hip_runtime.h>
#include <hip/hip_bf16.h>

#define B_ 4
#define S_ 1024
#define E_ 1280
#define H_ 16
#define D_ 80
#define M_ (B_*S_)   // 4096

typedef __hip_bfloat16 bf16;

__device__ __forceinline__ float b2f(bf16 x){ return __bfloat162float(x); }
__device__ __forceinline__ bf16  f2b(float x){ return __float2bfloat16(x); }

__device__ __forceinline__ float ldf(const float* p){ return *p; }
__device__ __forceinline__ float ldf(const bf16*  p){ return b2f(*p); }
__device__ __forceinline__ void  stf(float* p, float v){ *p = v; }
__device__ __forceinline__ void  stf(bf16*  p, float v){ *p = f2b(v); }

// C[m,n] = sum_k A[m,k]*W[n,k] + bias[n]   (A: MxK TA, W: NxK fp32)
// blockIdx.z selects (W, bias, C) -- does Q,K,V in one launch.
template<typename TA, typename TC>
__global__ __launch_bounds__(256) void gemm_nt_bias(
    const TA* __restrict__ A,
    const float* __restrict__ W0, const float* __restrict__ W1, const float* __restrict__ W2,
    const float* __restrict__ b0, const float* __restrict__ b1, const float* __restrict__ b2,
    TC* __restrict__ C0, TC* __restrict__ C1, TC* __restrict__ C2,
    int K, int N)
{
    const float* W; const float* bias; TC* C;
    if (blockIdx.z == 0)      { W = W0; bias = b0; C = C0; }
    else if (blockIdx.z == 1) { W = W1; bias = b1; C = C1; }
    else                      { W = W2; bias = b2; C = C2; }

    __shared__ float As[64][17];
    __shared__ float Ws[64][17];
    const int tid = threadIdx.x;
    const int tx = tid & 15, ty = tid >> 4;
    const int bm = blockIdx.x * 64, bn = blockIdx.y * 64;

    float acc[4][4] = {};

    for (int k0 = 0; k0 < K; k0 += 16) {
        #pragma unroll
        for (int i = 0; i < 4; i++) {
            int idx = tid + i * 256;
            int r = idx >> 4, c = idx & 15;
            As[r][c] = ldf(&A[(size_t)(bm + r) * K + k0 + c]);
            Ws[r][c] = W[(size_t)(bn + r) * K + k0 + c];
        }
        __syncthreads();
        #pragma unroll
        for (int kk = 0; kk < 16; kk++) {
            float a[4], w[4];
            #pragma unroll
            for (int i = 0; i < 4; i++) a[i] = As[ty*4 + i][kk];
            #pragma unroll
            for (int j = 0; j < 4; j++) w[j] = Ws[tx*4 + j][kk];
            #pragma unroll
            for (int i = 0; i < 4; i++)
                #pragma unroll
                for (int j = 0; j < 4; j++) acc[i][j] += a[i] * w[j];
        }
        __syncthreads();
    }

    #pragma unroll
    for (int i = 0; i < 4; i++) {
        int m = bm + ty*4 + i;
        #pragma unroll
        for (int j = 0; j < 4; j++) {
            int n = bn + tx*4 + j;
            stf(&C[(size_t)m * N + n], acc[i][j] + bias[n]);
        }
    }
}

// In-place RoPE on q and k (bf16 workspace). One thread per (j, j+40) pair.
__global__ void rope_kernel(bf16* __restrict__ q, bf16* __restrict__ k,
                            const float* __restrict__ cosp, const float* __restrict__ sinp)
{
    const int P = B_ * S_ * H_ * 40;
    int t = blockIdx.x * blockDim.x + threadIdx.x;
    if (t >= 2 * P) return;
    bf16* ten = (t < P) ? q : k;
    int r = (t < P) ? t : t - P;
    int j = r % 40;
    int h = (r / 40) % H_;
    int s = (r / (40 * H_)) % S_;
    int b = r / (40 * H_ * S_);
    size_t row = (size_t)(b * S_ + s) * E_;
    int c1 = h * D_ + j, c2 = c1 + 40;
    float cs = cosp[s * D_ + j];
    float sn = sinp[s * D_ + j];
    float q1 = b2f(ten[row + c1]), q2 = b2f(ten[row + c2]);
    ten[row + c1] = f2b(q1 * cs - q2 * sn);
    ten[row + c2] = f2b(q2 * cs + q1 * sn);
}

// Tiled flash-style attention.
// Block = (q-tile of 64 rows) x (head h) x (batch b). 256 threads.
// K/V staged in LDS in 32-key tiles; online softmax state per q-row in LDS.
// QK map: thread (tx=tid&15, ty=tid>>4) -> q rows ty*4..+3, k cols tx*2..+1.
// PV map: thread (dx=tid&15, qy=tid>>4) -> q rows qy*4..+3, dims dx*5..+4.
__global__ __launch_bounds__(256) void attn_tiled(
    const bf16* __restrict__ q, const bf16* __restrict__ k, const bf16* __restrict__ v,
    const int* __restrict__ cu, bf16* __restrict__ o)
{
    const int qt = blockIdx.x;
    const int h  = blockIdx.y;
    const int b  = blockIdx.z;
    const int tid = threadIdx.x;
    const int q0 = qt * 64;

    __shared__ float QT[80][68];   // Q transposed: QT[d][row]
    __shared__ float KT[80][36];   // K tile transposed: KT[d][key]
    __shared__ float Vs[32][84];   // V tile: Vs[key][d]
    __shared__ float PT[32][68];   // P transposed: PT[key][row]
    __shared__ float m_s[64], l_s[64], al_s[64];

    const int len = cu[b+1] - cu[b];

    // stage Q transposed (once)
    {
        const int row = tid >> 2;        // 0..63
        const int dg  = tid & 3;         // 4 groups of 20 d's
        const bf16* qp = q + (size_t)(b*S_ + q0 + row)*E_ + h*D_ + dg*20;
        #pragma unroll
        for (int u = 0; u < 20; u++)
            QT[dg*20 + u][row] = b2f(qp[u]);
    }
    if (tid < 64) { m_s[tid] = -1e30f; l_s[tid] = 0.f; }

    const int tx = tid & 15, ty = tid >> 4;
    const int dx = tx,       qy = ty;
    float o_acc[4][5] = {};
    const float scale = 0.11180339887498949f;  // 1/sqrt(80)

    for (int kt = 0; kt < 32; kt++) {
        __syncthreads();   // prev PV done reading KT/Vs/PT/al_s
        // stage KT (transposed) and Vs for this 32-key tile
        {
            const int key = tid >> 3;      // 0..31
            const int dg  = tid & 7;       // 8 groups of 10 d's
            const size_t gro = (size_t)(b*S_ + kt*32 + key)*E_ + h*D_ + dg*10;
            const bf16* kp = k + gro;
            const bf16* vp = v + gro;
            #pragma unroll
            for (int u = 0; u < 10; u++) {
                KT[dg*10+u][key] = b2f(kp[u]);
                Vs[key][dg*10+u] = b2f(vp[u]);
            }
        }
        __syncthreads();

        // ---- QK^T: s[4 q-rows][2 k-cols]
        float s_[4][2] = {};
        for (int d = 0; d < 80; d++) {
            float4 a  = *(const float4*)&QT[d][ty*4];
            float2 bb = *(const float2*)&KT[d][tx*2];
            s_[0][0] += a.x*bb.x; s_[0][1] += a.x*bb.y;
            s_[1][0] += a.y*bb.x; s_[1][1] += a.y*bb.y;
            s_[2][0] += a.z*bb.x; s_[2][1] += a.z*bb.y;
            s_[3][0] += a.w*bb.x; s_[3][1] += a.w*bb.y;
        }
        // mask + scale, per-thread row max
        float rmax[4], rsum[4], pp[4][2], mnew[4];
        #pragma unroll
        for (int i = 0; i < 4; i++) {
            const bool vq = (q0 + ty*4 + i) < len;
            #pragma unroll
            for (int j = 0; j < 2; j++) {
                const bool vk = (kt*32 + tx*2 + j) < len;
                s_[i][j] = (vq && vk) ? s_[i][j]*scale : -1e9f;
            }
            rmax[i] = fmaxf(s_[i][0], s_[i][1]);
        }
        #pragma unroll
        for (int st = 1; st < 16; st <<= 1)
            #pragma unroll
            for (int i = 0; i < 4; i++)
                rmax[i] = fmaxf(rmax[i], __shfl_xor(rmax[i], st, 64));
        #pragma unroll
        for (int i = 0; i < 4; i++) {
            mnew[i] = fmaxf(m_s[ty*4+i], rmax[i]);
            pp[i][0] = __expf(s_[i][0] - mnew[i]);
            pp[i][1] = __expf(s_[i][1] - mnew[i]);
            rsum[i] = pp[i][0] + pp[i][1];
        }
        #pragma unroll
        for (int st = 1; st < 16; st <<= 1)
            #pragma unroll
            for (int i = 0; i < 4; i++)
                rsum[i] += __shfl_xor(rsum[i], st, 64);
        if (tx == 0) {
            #pragma unroll
            for (int i = 0; i < 4; i++) {
                const int r = ty*4+i;
                const float a = __expf(m_s[r] - mnew[i]);
                al_s[r] = a;
                l_s[r]  = l_s[r]*a + rsum[i];
                m_s[r]  = mnew[i];
            }
        }
        // write P transposed: PT[col][row], float4 over 4 rows
        #pragma unroll
        for (int j = 0; j < 2; j++) {
            float4 pw = make_float4(pp[0][j], pp[1][j], pp[2][j], pp[3][j]);
            *(float4*)&PT[tx*2+j][ty*4] = pw;
        }
        __syncthreads();

        // ---- PV: o[4 q-rows][5 dims]
        float al[4];
        #pragma unroll
        for (int i = 0; i < 4; i++) al[i] = al_s[qy*4+i];
        #pragma unroll
        for (int i = 0; i < 4; i++)
            #pragma unroll
            for (int r = 0; r < 5; r++) o_acc[i][r] *= al[i];
        for (int kk = 0; kk < 32; kk++) {
            float4 a = *(const float4*)&PT[kk][qy*4];
            float vv_[5];
            #pragma unroll
            for (int r = 0; r < 5; r++) vv_[r] = Vs[kk][dx*5+r];
            #pragma unroll
            for (int r = 0; r < 5; r++) {
                o_acc[0][r] += a.x*vv_[r];
                o_acc[1][r] += a.y*vv_[r];
                o_acc[2][r] += a.z*vv_[r];
                o_acc[3][r] += a.w*vv_[r];
            }
        }
    }
    __syncthreads();
    #pragma unroll
    for (int i = 0; i < 4; i++) {
        const int r = qy*4+i;
        const float inv = 1.0f / l_s[r];
        bf16* op = o + (size_t)(b*S_ + q0 + r)*E_ + h*D_ + dx*5;
        #pragma unroll
        for (int rr = 0; rr < 5; rr++)
            op[rr] = f2b(o_acc[i][rr]*inv);
    }
}

extern "C" void kernel_launch(void* const* d_in, const int* in_sizes, int n_in,
                              void* d_out, int out_size, void* d_ws, size_t ws_size,
                              hipStream_t stream)
{
    const float* x    = (const float*)d_in[0];
    const int*   cu   = (const int*)  d_in[1];
    const float* cosp = (const float*)d_in[2];
    const float* sinp = (const float*)d_in[3];
    const float* wq   = (const float*)d_in[4];
    const float* bq   = (const float*)d_in[5];
    const float* wk   = (const float*)d_in[6];
    const float* bk   = (const float*)d_in[7];
    const float* wv   = (const float*)d_in[8];
    const float* bv   = (const float*)d_in[9];
    const float* wo   = (const float*)d_in[10];
    const float* bo   = (const float*)d_in[11];
    float* out = (float*)d_out;

    // workspace (bf16): q, k, v, attn_out -- each 10.5 MB, total 42 MB
    bf16* q  = (bf16*)d_ws;
    bf16* kk = q  + (size_t)M_ * E_;
    bf16* vv = kk + (size_t)M_ * E_;
    bf16* ao = vv + (size_t)M_ * E_;

    // 1) QKV projection
    dim3 g1(M_ / 64, E_ / 64, 3);
    gemm_nt_bias<float, bf16><<<g1, 256, 0, stream>>>(
        x, wq, wk, wv, bq, bk, bv, q, kk, vv, E_, E_);

    // 2) RoPE in place on q and k
    int P2 = 2 * B_ * S_ * H_ * 40;
    rope_kernel<<<(P2 + 255) / 256, 256, 0, stream>>>(q, kk, cosp, sinp);

    // 3) tiled attention
    attn_tiled<<<dim3(S_/64, H_, B_), 256, 0, stream>>>(q, kk, vv, cu, ao);

    // 4) output projection
    dim3 g2(M_ / 64, E_ / 64, 1);
    gemm_nt_bias<bf16, float><<<g2, 256, 0, stream>>>(
        ao, wo, wo, wo, bo, bo, bo, out, out, out, E_, E_);
}

// Round 4
// 670.020 us; speedup vs baseline: 12.7096x; 2.5507x over previous
//
#include <hip/hip_runtime.h>
#include <hip/hip_bf16.h>

#define B_ 4
#define S_ 1024
#define E_ 1280
#define H_ 16
#define D_ 80
#define M_ (B_*S_)   // 4096

typedef __hip_bfloat16 bf16;
using bf16x8 = __attribute__((ext_vector_type(8))) short;  // 8 bf16 = 4 VGPRs
using f32x4  = __attribute__((ext_vector_type(4))) float;  // MFMA C/D frag

__device__ __forceinline__ float b2f(bf16 x){ return __bfloat162float(x); }
__device__ __forceinline__ bf16  f2b(float x){ return __float2bfloat16(x); }
__device__ __forceinline__ void  stf(float* p, float v){ *p = v; }
__device__ __forceinline__ void  stf(bf16*  p, float v){ *p = f2b(v); }

__device__ __forceinline__ void gload_lds16(const void* g, void* l) {
    __builtin_amdgcn_global_load_lds(
        (const __attribute__((address_space(1))) unsigned int*)g,
        (__attribute__((address_space(3))) unsigned int*)l, 16, 0, 0);
}

// fp32 -> bf16 conversion, 8 elems/thread. blockIdx.y selects segment.
__global__ __launch_bounds__(256) void cvt_kernel(
    const float* __restrict__ s0, const float* __restrict__ s1,
    const float* __restrict__ s2, const float* __restrict__ s3,
    const float* __restrict__ s4,
    bf16* __restrict__ d0, bf16* __restrict__ d1, bf16* __restrict__ d2,
    bf16* __restrict__ d3, bf16* __restrict__ d4,
    int n0, int n1)
{
    const float* s; bf16* d; int n;
    switch (blockIdx.y) {
        case 0: s = s0; d = d0; n = n0; break;
        case 1: s = s1; d = d1; n = n1; break;
        case 2: s = s2; d = d2; n = n1; break;
        case 3: s = s3; d = d3; n = n1; break;
        default: s = s4; d = d4; n = n1; break;
    }
    int i = (blockIdx.x * 256 + threadIdx.x) * 8;
    if (i >= n) return;
    float4 a = *(const float4*)(s + i);
    float4 b = *(const float4*)(s + i + 4);
    bf16 t[8];
    t[0]=f2b(a.x); t[1]=f2b(a.y); t[2]=f2b(a.z); t[3]=f2b(a.w);
    t[4]=f2b(b.x); t[5]=f2b(b.y); t[6]=f2b(b.z); t[7]=f2b(b.w);
    *(uint4*)(d + i) = *(const uint4*)t;
}

// m97-style MFMA GEMM: C[m,n] = sum_k A[m,k]*W[n,k] + bias[n]
// A: [M,K] bf16, W: [N,K] bf16 (K contiguous both), bias fp32.
// 128x128 tile, BK=32, 256 threads = 4 waves, each wave 64x64 (4x4 of 16x16x32).
// blockIdx.y = mat*ntiles + ntile  (mat selects W/bias/C).
template<typename TC>
__global__ __launch_bounds__(256) void mfma_gemm_bt(
    const bf16* __restrict__ A,
    const bf16* __restrict__ W0, const bf16* __restrict__ W1, const bf16* __restrict__ W2,
    const float* __restrict__ b0, const float* __restrict__ b1, const float* __restrict__ b2,
    TC* __restrict__ C0, TC* __restrict__ C1, TC* __restrict__ C2,
    int K, int N, int ntiles)
{
    const int mat = blockIdx.y / ntiles;
    const int bn  = (blockIdx.y % ntiles) * 128;
    const int bm  = blockIdx.x * 128;
    const bf16* W; const float* bias; TC* C;
    if (mat == 0)      { W = W0; bias = b0; C = C0; }
    else if (mat == 1) { W = W1; bias = b1; C = C1; }
    else               { W = W2; bias = b2; C = C2; }

    // NOTE: no padding -- global_load_lds lands lane l at base + l*16B,
    // so LDS must be packed row-major [row][32] (64 B rows).
    __shared__ bf16 As[128][32];
    __shared__ bf16 Ws[128][32];

    const int tid  = threadIdx.x;
    const int lane = tid & 63;
    const int wv   = tid >> 6;          // wave 0..3
    const int wm   = (wv & 1) * 64;     // wave row offset in tile
    const int wn   = (wv >> 1) * 64;    // wave col offset in tile

    // staging coords: wave's 16-row chunk, lane l -> row l/4, col8 (l%4)*8
    const int srow = wv * 16 + (lane >> 2);
    const int scol = (lane & 3) * 8;

    f32x4 acc[4][4] = {};   // acc[mt][nt]

    for (int k0 = 0; k0 < K; k0 += 32) {
        __syncthreads();   // previous compute done reading LDS
        gload_lds16(A + (size_t)(bm + srow)      * K + k0 + scol, &As[wv*16][0]);
        gload_lds16(A + (size_t)(bm + 64 + srow) * K + k0 + scol, &As[64 + wv*16][0]);
        gload_lds16(W + (size_t)(bn + srow)      * K + k0 + scol, &Ws[wv*16][0]);
        gload_lds16(W + (size_t)(bn + 64 + srow) * K + k0 + scol, &Ws[64 + wv*16][0]);
        __syncthreads();   // drains vmcnt before barrier (compiler-emitted)

        const int fr = lane & 15;         // row within 16-tile
        const int kq = (lane >> 4) * 8;   // k offset (quad*8)
        bf16x8 af[4], wf[4];
        #pragma unroll
        for (int t = 0; t < 4; t++) {
            af[t] = *(const bf16x8*)&As[wm + t*16 + fr][kq];
            wf[t] = *(const bf16x8*)&Ws[wn + t*16 + fr][kq];
        }
        #pragma unroll
        for (int mt = 0; mt < 4; mt++)
            #pragma unroll
            for (int nt = 0; nt < 4; nt++)
                acc[mt][nt] = __builtin_amdgcn_mfma_f32_16x16x32_bf16(
                    af[mt], wf[nt], acc[mt][nt], 0, 0, 0);
    }

    // epilogue: C/D layout col=lane&15, row=(lane>>4)*4+reg  [m89/m91]
    const int col_l = lane & 15;
    const int row_l = (lane >> 4) * 4;
    #pragma unroll
    for (int nt = 0; nt < 4; nt++) {
        const int n = bn + wn + nt*16 + col_l;
        const float bv = bias[n];
        #pragma unroll
        for (int mt = 0; mt < 4; mt++) {
            #pragma unroll
            for (int r = 0; r < 4; r++) {
                const int m = bm + wm + mt*16 + row_l + r;
                stf(&C[(size_t)m * N + n], acc[mt][nt][r] + bv);
            }
        }
    }
}

// In-place RoPE on q and k (bf16 ws). One thread per (j, j+40) pair.
__global__ void rope_kernel(bf16* __restrict__ q, bf16* __restrict__ k,
                            const float* __restrict__ cosp, const float* __restrict__ sinp)
{
    const int P = B_ * S_ * H_ * 40;
    int t = blockIdx.x * blockDim.x + threadIdx.x;
    if (t >= 2 * P) return;
    bf16* ten = (t < P) ? q : k;
    int r = (t < P) ? t : t - P;
    int j = r % 40;
    int h = (r / 40) % H_;
    int s = (r / (40 * H_)) % S_;
    int b = r / (40 * H_ * S_);
    size_t row = (size_t)(b * S_ + s) * E_;
    int c1 = h * D_ + j, c2 = c1 + 40;
    float cs = cosp[s * D_ + j];
    float sn = sinp[s * D_ + j];
    float q1 = b2f(ten[row + c1]), q2 = b2f(ten[row + c2]);
    ten[row + c1] = f2b(q1 * cs - q2 * sn);
    ten[row + c2] = f2b(q2 * cs + q1 * sn);
}

// Tiled flash-style attention (unchanged from round 2).
__global__ __launch_bounds__(256) void attn_tiled(
    const bf16* __restrict__ q, const bf16* __restrict__ k, const bf16* __restrict__ v,
    const int* __restrict__ cu, bf16* __restrict__ o)
{
    const int qt = blockIdx.x;
    const int h  = blockIdx.y;
    const int b  = blockIdx.z;
    const int tid = threadIdx.x;
    const int q0 = qt * 64;

    __shared__ float QT[80][68];
    __shared__ float KT[80][36];
    __shared__ float Vs[32][84];
    __shared__ float PT[32][68];
    __shared__ float m_s[64], l_s[64], al_s[64];

    const int len = cu[b+1] - cu[b];

    {
        const int row = tid >> 2;
        const int dg  = tid & 3;
        const bf16* qp = q + (size_t)(b*S_ + q0 + row)*E_ + h*D_ + dg*20;
        #pragma unroll
        for (int u = 0; u < 20; u++)
            QT[dg*20 + u][row] = b2f(qp[u]);
    }
    if (tid < 64) { m_s[tid] = -1e30f; l_s[tid] = 0.f; }

    const int tx = tid & 15, ty = tid >> 4;
    const int dx = tx,       qy = ty;
    float o_acc[4][5] = {};
    const float scale = 0.11180339887498949f;

    for (int kt = 0; kt < 32; kt++) {
        __syncthreads();
        {
            const int key = tid >> 3;
            const int dg  = tid & 7;
            const size_t gro = (size_t)(b*S_ + kt*32 + key)*E_ + h*D_ + dg*10;
            const bf16* kp = k + gro;
            const bf16* vp = v + gro;
            #pragma unroll
            for (int u = 0; u < 10; u++) {
                KT[dg*10+u][key] = b2f(kp[u]);
                Vs[key][dg*10+u] = b2f(vp[u]);
            }
        }
        __syncthreads();

        float s_[4][2] = {};
        for (int d = 0; d < 80; d++) {
            float4 a  = *(const float4*)&QT[d][ty*4];
            float2 bb = *(const float2*)&KT[d][tx*2];
            s_[0][0] += a.x*bb.x; s_[0][1] += a.x*bb.y;
            s_[1][0] += a.y*bb.x; s_[1][1] += a.y*bb.y;
            s_[2][0] += a.z*bb.x; s_[2][1] += a.z*bb.y;
            s_[3][0] += a.w*bb.x; s_[3][1] += a.w*bb.y;
        }
        float rmax[4], rsum[4], pp[4][2], mnew[4];
        #pragma unroll
        for (int i = 0; i < 4; i++) {
            const bool vq = (q0 + ty*4 + i) < len;
            #pragma unroll
            for (int j = 0; j < 2; j++) {
                const bool vk = (kt*32 + tx*2 + j) < len;
                s_[i][j] = (vq && vk) ? s_[i][j]*scale : -1e9f;
            }
            rmax[i] = fmaxf(s_[i][0], s_[i][1]);
        }
        #pragma unroll
        for (int st = 1; st < 16; st <<= 1)
            #pragma unroll
            for (int i = 0; i < 4; i++)
                rmax[i] = fmaxf(rmax[i], __shfl_xor(rmax[i], st, 64));
        #pragma unroll
        for (int i = 0; i < 4; i++) {
            mnew[i] = fmaxf(m_s[ty*4+i], rmax[i]);
            pp[i][0] = __expf(s_[i][0] - mnew[i]);
            pp[i][1] = __expf(s_[i][1] - mnew[i]);
            rsum[i] = pp[i][0] + pp[i][1];
        }
        #pragma unroll
        for (int st = 1; st < 16; st <<= 1)
            #pragma unroll
            for (int i = 0; i < 4; i++)
                rsum[i] += __shfl_xor(rsum[i], st, 64);
        if (tx == 0) {
            #pragma unroll
            for (int i = 0; i < 4; i++) {
                const int r = ty*4+i;
                const float a = __expf(m_s[r] - mnew[i]);
                al_s[r] = a;
                l_s[r]  = l_s[r]*a + rsum[i];
                m_s[r]  = mnew[i];
            }
        }
        #pragma unroll
        for (int j = 0; j < 2; j++) {
            float4 pw = make_float4(pp[0][j], pp[1][j], pp[2][j], pp[3][j]);
            *(float4*)&PT[tx*2+j][ty*4] = pw;
        }
        __syncthreads();

        float al[4];
        #pragma unroll
        for (int i = 0; i < 4; i++) al[i] = al_s[qy*4+i];
        #pragma unroll
        for (int i = 0; i < 4; i++)
            #pragma unroll
            for (int r = 0; r < 5; r++) o_acc[i][r] *= al[i];
        for (int kk = 0; kk < 32; kk++) {
            float4 a = *(const float4*)&PT[kk][qy*4];
            float vv_[5];
            #pragma unroll
            for (int r = 0; r < 5; r++) vv_[r] = Vs[kk][dx*5+r];
            #pragma unroll
            for (int r = 0; r < 5; r++) {
                o_acc[0][r] += a.x*vv_[r];
                o_acc[1][r] += a.y*vv_[r];
                o_acc[2][r] += a.z*vv_[r];
                o_acc[3][r] += a.w*vv_[r];
            }
        }
    }
    __syncthreads();
    #pragma unroll
    for (int i = 0; i < 4; i++) {
        const int r = qy*4+i;
        const float inv = 1.0f / l_s[r];
        bf16* op = o + (size_t)(b*S_ + q0 + r)*E_ + h*D_ + dx*5;
        #pragma unroll
        for (int rr = 0; rr < 5; rr++)
            op[rr] = f2b(o_acc[i][rr]*inv);
    }
}

extern "C" void kernel_launch(void* const* d_in, const int* in_sizes, int n_in,
                              void* d_out, int out_size, void* d_ws, size_t ws_size,
                              hipStream_t stream)
{
    const float* x    = (const float*)d_in[0];
    const int*   cu   = (const int*)  d_in[1];
    const float* cosp = (const float*)d_in[2];
    const float* sinp = (const float*)d_in[3];
    const float* wq   = (const float*)d_in[4];
    const float* bq   = (const float*)d_in[5];
    const float* wk   = (const float*)d_in[6];
    const float* bk   = (const float*)d_in[7];
    const float* wv   = (const float*)d_in[8];
    const float* bv   = (const float*)d_in[9];
    const float* wo   = (const float*)d_in[10];
    const float* bo   = (const float*)d_in[11];
    float* out = (float*)d_out;

    // ws (bf16): q,k,v,ao (4 x 5242880), xb (5242880), wqb..wob (4 x 1638400)
    bf16* q   = (bf16*)d_ws;
    bf16* kk  = q   + (size_t)M_ * E_;
    bf16* vv  = kk  + (size_t)M_ * E_;
    bf16* ao  = vv  + (size_t)M_ * E_;
    bf16* xb  = ao  + (size_t)M_ * E_;
    bf16* wqb = xb  + (size_t)M_ * E_;
    bf16* wkb = wqb + (size_t)E_ * E_;
    bf16* wvb = wkb + (size_t)E_ * E_;
    bf16* wob = wvb + (size_t)E_ * E_;

    // 0) convert x + 4 weight matrices to bf16
    cvt_kernel<<<dim3(2560, 5), 256, 0, stream>>>(
        x, wq, wk, wv, wo, xb, wqb, wkb, wvb, wob, M_*E_, E_*E_);

    // 1) QKV projection (MFMA), bias fused
    mfma_gemm_bt<bf16><<<dim3(M_/128, 30), 256, 0, stream>>>(
        xb, wqb, wkb, wvb, bq, bk, bv, q, kk, vv, E_, E_, 10);

    // 2) RoPE in place on q and k
    int P2 = 2 * B_ * S_ * H_ * 40;
    rope_kernel<<<(P2 + 255) / 256, 256, 0, stream>>>(q, kk, cosp, sinp);

    // 3) tiled attention
    attn_tiled<<<dim3(S_/64, H_, B_), 256, 0, stream>>>(q, kk, vv, cu, ao);

    // 4) output projection (MFMA), fp32 out, bias fused
    mfma_gemm_bt<float><<<dim3(M_/128, 10), 256, 0, stream>>>(
        ao, wob, wob, wob, bo, bo, bo, out, out, out, E_, E_, 10);
}

// Round 5
// 307.725 us; speedup vs baseline: 27.6731x; 2.1773x over previous
//
#include <hip/hip_runtime.h>
#include <hip/hip_bf16.h>

#define B_ 4
#define S_ 1024
#define E_ 1280
#define H_ 16
#define D_ 80
#define M_ (B_*S_)   // 4096

typedef __hip_bfloat16 bf16;
using bf16x8 = __attribute__((ext_vector_type(8))) short;  // 8 bf16 = 4 VGPRs
using f32x4  = __attribute__((ext_vector_type(4))) float;  // MFMA C/D frag

__device__ __forceinline__ float b2f(bf16 x){ return __bfloat162float(x); }
__device__ __forceinline__ bf16  f2b(float x){ return __float2bfloat16(x); }
__device__ __forceinline__ void  stf(float* p, float v){ *p = v; }
__device__ __forceinline__ void  stf(bf16*  p, float v){ *p = f2b(v); }

__device__ __forceinline__ void gload_lds16(const void* g, void* l) {
    __builtin_amdgcn_global_load_lds(
        (const __attribute__((address_space(1))) unsigned int*)g,
        (__attribute__((address_space(3))) unsigned int*)l, 16, 0, 0);
}

// fp32 -> bf16 conversion, 8 elems/thread. blockIdx.y selects segment.
__global__ __launch_bounds__(256) void cvt_kernel(
    const float* __restrict__ s0, const float* __restrict__ s1,
    const float* __restrict__ s2, const float* __restrict__ s3,
    const float* __restrict__ s4,
    bf16* __restrict__ d0, bf16* __restrict__ d1, bf16* __restrict__ d2,
    bf16* __restrict__ d3, bf16* __restrict__ d4,
    int n0, int n1)
{
    const float* s; bf16* d; int n;
    switch (blockIdx.y) {
        case 0: s = s0; d = d0; n = n0; break;
        case 1: s = s1; d = d1; n = n1; break;
        case 2: s = s2; d = d2; n = n1; break;
        case 3: s = s3; d = d3; n = n1; break;
        default: s = s4; d = d4; n = n1; break;
    }
    int i = (blockIdx.x * 256 + threadIdx.x) * 8;
    if (i >= n) return;
    float4 a = *(const float4*)(s + i);
    float4 b = *(const float4*)(s + i + 4);
    bf16 t[8];
    t[0]=f2b(a.x); t[1]=f2b(a.y); t[2]=f2b(a.z); t[3]=f2b(a.w);
    t[4]=f2b(b.x); t[5]=f2b(b.y); t[6]=f2b(b.z); t[7]=f2b(b.w);
    *(uint4*)(d + i) = *(const uint4*)t;
}

// m97-style MFMA GEMM: C[m,n] = sum_k A[m,k]*W[n,k] + bias[n]
template<typename TC>
__global__ __launch_bounds__(256) void mfma_gemm_bt(
    const bf16* __restrict__ A,
    const bf16* __restrict__ W0, const bf16* __restrict__ W1, const bf16* __restrict__ W2,
    const float* __restrict__ b0, const float* __restrict__ b1, const float* __restrict__ b2,
    TC* __restrict__ C0, TC* __restrict__ C1, TC* __restrict__ C2,
    int K, int N, int ntiles)
{
    const int mat = blockIdx.y / ntiles;
    const int bn  = (blockIdx.y % ntiles) * 128;
    const int bm  = blockIdx.x * 128;
    const bf16* W; const float* bias; TC* C;
    if (mat == 0)      { W = W0; bias = b0; C = C0; }
    else if (mat == 1) { W = W1; bias = b1; C = C1; }
    else               { W = W2; bias = b2; C = C2; }

    __shared__ bf16 As[128][32];
    __shared__ bf16 Ws[128][32];

    const int tid  = threadIdx.x;
    const int lane = tid & 63;
    const int wv   = tid >> 6;
    const int wm   = (wv & 1) * 64;
    const int wn   = (wv >> 1) * 64;
    const int srow = wv * 16 + (lane >> 2);
    const int scol = (lane & 3) * 8;

    f32x4 acc[4][4] = {};

    for (int k0 = 0; k0 < K; k0 += 32) {
        __syncthreads();
        gload_lds16(A + (size_t)(bm + srow)      * K + k0 + scol, &As[wv*16][0]);
        gload_lds16(A + (size_t)(bm + 64 + srow) * K + k0 + scol, &As[64 + wv*16][0]);
        gload_lds16(W + (size_t)(bn + srow)      * K + k0 + scol, &Ws[wv*16][0]);
        gload_lds16(W + (size_t)(bn + 64 + srow) * K + k0 + scol, &Ws[64 + wv*16][0]);
        __syncthreads();

        const int fr = lane & 15;
        const int kq = (lane >> 4) * 8;
        bf16x8 af[4], wf[4];
        #pragma unroll
        for (int t = 0; t < 4; t++) {
            af[t] = *(const bf16x8*)&As[wm + t*16 + fr][kq];
            wf[t] = *(const bf16x8*)&Ws[wn + t*16 + fr][kq];
        }
        #pragma unroll
        for (int mt = 0; mt < 4; mt++)
            #pragma unroll
            for (int nt = 0; nt < 4; nt++)
                acc[mt][nt] = __builtin_amdgcn_mfma_f32_16x16x32_bf16(
                    af[mt], wf[nt], acc[mt][nt], 0, 0, 0);
    }

    const int col_l = lane & 15;
    const int row_l = (lane >> 4) * 4;
    #pragma unroll
    for (int nt = 0; nt < 4; nt++) {
        const int n = bn + wn + nt*16 + col_l;
        const float bv = bias[n];
        #pragma unroll
        for (int mt = 0; mt < 4; mt++) {
            #pragma unroll
            for (int r = 0; r < 4; r++) {
                const int m = bm + wm + mt*16 + row_l + r;
                stf(&C[(size_t)m * N + n], acc[mt][nt][r] + bv);
            }
        }
    }
}

// In-place RoPE on q and k (bf16 ws). One thread per (j, j+40) pair.
__global__ void rope_kernel(bf16* __restrict__ q, bf16* __restrict__ k,
                            const float* __restrict__ cosp, const float* __restrict__ sinp)
{
    const int P = B_ * S_ * H_ * 40;
    int t = blockIdx.x * blockDim.x + threadIdx.x;
    if (t >= 2 * P) return;
    bf16* ten = (t < P) ? q : k;
    int r = (t < P) ? t : t - P;
    int j = r % 40;
    int h = (r / 40) % H_;
    int s = (r / (40 * H_)) % S_;
    int b = r / (40 * H_ * S_);
    size_t row = (size_t)(b * S_ + s) * E_;
    int c1 = h * D_ + j, c2 = c1 + 40;
    float cs = cosp[s * D_ + j];
    float sn = sinp[s * D_ + j];
    float q1 = b2f(ten[row + c1]), q2 = b2f(ten[row + c2]);
    ten[row + c1] = f2b(q1 * cs - q2 * sn);
    ten[row + c2] = f2b(q2 * cs + q1 * sn);
}

// MFMA flash attention. Block = 64 q-rows x (head, batch). 4 waves.
// Wave w owns q-rows [w*16, w*16+16); softmax state in registers.
// K-tile = 64 keys. QK: 3 ksteps of 16x16x32 (D=80 zero-padded to 96).
// PV: P->LDS(A-layout) round-trip; V B-frags as 8x ds_read_u16.
__global__ __launch_bounds__(256, 4) void attn_mfma(
    const bf16* __restrict__ q, const bf16* __restrict__ k, const bf16* __restrict__ v,
    const int* __restrict__ cu, bf16* __restrict__ o)
{
    // LDS: Qs[64][104] @0 (13312 B), Ks[64][104] @13312, Vs[64][84] @26624 (10752 B)
    // PT (per-wave [16][72], 2304 B) aliases Qs (Q frags are in regs before first PT write).
    __shared__ __align__(16) char smem[37376];
    bf16* Qs = (bf16*)smem;
    bf16* Ks = (bf16*)(smem + 13312);
    bf16* Vs = (bf16*)(smem + 26624);

    const int qt = blockIdx.x, h = blockIdx.y, b = blockIdx.z;
    const int tid = threadIdx.x;
    const int lane = tid & 63, wv = tid >> 6;
    const int quad = lane >> 4, l15 = lane & 15;
    const int q0 = qt * 64;
    const int len = cu[b + 1] - cu[b];
    const float scale = 0.11180339887498949f;  // 1/sqrt(80), folded into Q

    // ---- stage Q (pre-scaled): 64 rows x 80 cols in 16B chunks (640)
    #pragma unroll
    for (int i = 0; i < 3; i++) {
        int c = tid + i * 256;
        if (c < 640) {
            int row = c / 10, c8 = c % 10;
            const bf16* src = q + (size_t)(b*S_ + q0 + row)*E_ + h*D_ + c8*8;
            union { uint4 u; bf16 h[8]; } in, ot;
            in.u = *(const uint4*)src;
            #pragma unroll
            for (int u = 0; u < 8; u++) ot.h[u] = f2b(b2f(in.h[u]) * scale);
            *(uint4*)&Qs[row*104 + c8*8] = ot.u;
        }
    }
    // zero pad cols 80..95 of Qs and Ks (K staging never writes them)
    if (tid < 128) {
        int row = tid >> 1, c8 = 10 + (tid & 1);
        uint4 z = make_uint4(0,0,0,0);
        *(uint4*)&Qs[row*104 + c8*8] = z;
        *(uint4*)&Ks[row*104 + c8*8] = z;
    }
    __syncthreads();

    // ---- Q A-frags to registers (3 ksteps)
    bf16x8 qf[3];
    #pragma unroll
    for (int ks = 0; ks < 3; ks++)
        qf[ks] = *(const bf16x8*)&Qs[(wv*16 + l15)*104 + ks*32 + quad*8];

    float m_r[4], l_r[4];
    #pragma unroll
    for (int r = 0; r < 4; r++) { m_r[r] = -1e30f; l_r[r] = 0.f; }
    f32x4 o_acc[5] = {};
    bf16* PT = (bf16*)(smem + wv * 2304);   // [16][72]

    for (int kt = 0; kt < 16; kt++) {
        __syncthreads();   // prev tile's LDS reads done; also protects Qs->PT alias on kt=0
        // stage K tile
        #pragma unroll
        for (int i = 0; i < 3; i++) {
            int c = tid + i * 256;
            if (c < 640) {
                int row = c / 10, c8 = c % 10;
                const bf16* src = k + (size_t)(b*S_ + kt*64 + row)*E_ + h*D_ + c8*8;
                *(uint4*)&Ks[row*104 + c8*8] = *(const uint4*)src;
            }
        }
        // stage V tile (8B chunks, 1280 = 5*256)
        #pragma unroll
        for (int i = 0; i < 5; i++) {
            int c = tid + i * 256;
            int row = c / 20, c4 = c % 20;
            const bf16* src = v + (size_t)(b*S_ + kt*64 + row)*E_ + h*D_ + c4*4;
            *(uint2*)&Vs[row*84 + c4*4] = *(const uint2*)src;
        }
        __syncthreads();

        // ---- QK^T: 4 n-tiles of 16 keys
        f32x4 s4[4];
        #pragma unroll
        for (int nt = 0; nt < 4; nt++) {
            f32x4 cacc = {};
            #pragma unroll
            for (int ks = 0; ks < 3; ks++) {
                bf16x8 kf = *(const bf16x8*)&Ks[(nt*16 + l15)*104 + ks*32 + quad*8];
                cacc = __builtin_amdgcn_mfma_f32_16x16x32_bf16(qf[ks], kf, cacc, 0, 0, 0);
            }
            s4[nt] = cacc;
        }

        // ---- mask + online softmax (rows quad*4+r, wave-exclusive)
        float sv[4][4];
        bool vk[4];
        #pragma unroll
        for (int nt = 0; nt < 4; nt++) vk[nt] = (kt*64 + nt*16 + l15) < len;
        #pragma unroll
        for (int r = 0; r < 4; r++) {
            const bool vq = (q0 + wv*16 + quad*4 + r) < len;
            #pragma unroll
            for (int nt = 0; nt < 4; nt++)
                sv[nt][r] = (vq && vk[nt]) ? s4[nt][r] : -1e9f;
        }
        float rmax[4];
        #pragma unroll
        for (int r = 0; r < 4; r++)
            rmax[r] = fmaxf(fmaxf(sv[0][r], sv[1][r]), fmaxf(sv[2][r], sv[3][r]));
        #pragma unroll
        for (int st = 1; st < 16; st <<= 1)
            #pragma unroll
            for (int r = 0; r < 4; r++)
                rmax[r] = fmaxf(rmax[r], __shfl_xor(rmax[r], st, 64));
        float mnew[4], alpha[4], rsum[4], p[4][4];
        #pragma unroll
        for (int r = 0; r < 4; r++) {
            mnew[r]  = fmaxf(m_r[r], rmax[r]);
            alpha[r] = __expf(m_r[r] - mnew[r]);
            float a = 0.f;
            #pragma unroll
            for (int nt = 0; nt < 4; nt++) { p[nt][r] = __expf(sv[nt][r] - mnew[r]); a += p[nt][r]; }
            rsum[r] = a;
        }
        #pragma unroll
        for (int st = 1; st < 16; st <<= 1)
            #pragma unroll
            for (int r = 0; r < 4; r++)
                rsum[r] += __shfl_xor(rsum[r], st, 64);
        #pragma unroll
        for (int r = 0; r < 4; r++) {
            l_r[r] = l_r[r] * alpha[r] + rsum[r];
            m_r[r] = mnew[r];
        }
        #pragma unroll
        for (int dt = 0; dt < 5; dt++)
            #pragma unroll
            for (int r = 0; r < 4; r++)
                o_acc[dt][r] *= alpha[r];

        // ---- P (C-layout) -> PT (A-layout) via per-wave LDS
        #pragma unroll
        for (int nt = 0; nt < 4; nt++)
            #pragma unroll
            for (int r = 0; r < 4; r++)
                PT[(quad*4 + r)*72 + nt*16 + l15] = f2b(p[nt][r]);
        // same-wave LDS RAW: DS ops in-order + compiler lgkmcnt waits

        // ---- PV: 5 d-tiles x 2 ksteps
        bf16x8 pa0 = *(const bf16x8*)&PT[l15*72 + quad*8];
        bf16x8 pa1 = *(const bf16x8*)&PT[l15*72 + 32 + quad*8];
        #pragma unroll
        for (int dt = 0; dt < 5; dt++) {
            union { bf16 h[8]; bf16x8 v; } vf0, vf1;
            #pragma unroll
            for (int j = 0; j < 8; j++) vf0.h[j] = Vs[(quad*8 + j)*84 + dt*16 + l15];
            o_acc[dt] = __builtin_amdgcn_mfma_f32_16x16x32_bf16(pa0, vf0.v, o_acc[dt], 0, 0, 0);
            #pragma unroll
            for (int j = 0; j < 8; j++) vf1.h[j] = Vs[(32 + quad*8 + j)*84 + dt*16 + l15];
            o_acc[dt] = __builtin_amdgcn_mfma_f32_16x16x32_bf16(pa1, vf1.v, o_acc[dt], 0, 0, 0);
        }
    }

    // ---- epilogue
    float inv[4];
    #pragma unroll
    for (int r = 0; r < 4; r++) inv[r] = 1.0f / l_r[r];
    #pragma unroll
    for (int dt = 0; dt < 5; dt++)
        #pragma unroll
        for (int r = 0; r < 4; r++) {
            size_t row_g = (size_t)(b*S_ + q0 + wv*16 + quad*4 + r);
            o[row_g*E_ + h*D_ + dt*16 + l15] = f2b(o_acc[dt][r] * inv[r]);
        }
}

extern "C" void kernel_launch(void* const* d_in, const int* in_sizes, int n_in,
                              void* d_out, int out_size, void* d_ws, size_t ws_size,
                              hipStream_t stream)
{
    const float* x    = (const float*)d_in[0];
    const int*   cu   = (const int*)  d_in[1];
    const float* cosp = (const float*)d_in[2];
    const float* sinp = (const float*)d_in[3];
    const float* wq   = (const float*)d_in[4];
    const float* bq   = (const float*)d_in[5];
    const float* wk   = (const float*)d_in[6];
    const float* bk   = (const float*)d_in[7];
    const float* wv   = (const float*)d_in[8];
    const float* bv   = (const float*)d_in[9];
    const float* wo   = (const float*)d_in[10];
    const float* bo   = (const float*)d_in[11];
    float* out = (float*)d_out;

    bf16* q   = (bf16*)d_ws;
    bf16* kk  = q   + (size_t)M_ * E_;
    bf16* vv  = kk  + (size_t)M_ * E_;
    bf16* ao  = vv  + (size_t)M_ * E_;
    bf16* xb  = ao  + (size_t)M_ * E_;
    bf16* wqb = xb  + (size_t)M_ * E_;
    bf16* wkb = wqb + (size_t)E_ * E_;
    bf16* wvb = wkb + (size_t)E_ * E_;
    bf16* wob = wvb + (size_t)E_ * E_;

    // 0) convert x + 4 weight matrices to bf16
    cvt_kernel<<<dim3(2560, 5), 256, 0, stream>>>(
        x, wq, wk, wv, wo, xb, wqb, wkb, wvb, wob, M_*E_, E_*E_);

    // 1) QKV projection (MFMA), bias fused
    mfma_gemm_bt<bf16><<<dim3(M_/128, 30), 256, 0, stream>>>(
        xb, wqb, wkb, wvb, bq, bk, bv, q, kk, vv, E_, E_, 10);

    // 2) RoPE in place on q and k
    int P2 = 2 * B_ * S_ * H_ * 40;
    rope_kernel<<<(P2 + 255) / 256, 256, 0, stream>>>(q, kk, cosp, sinp);

    // 3) MFMA flash attention
    attn_mfma<<<dim3(S_/64, H_, B_), 256, 0, stream>>>(q, kk, vv, cu, ao);

    // 4) output projection (MFMA), fp32 out, bias fused
    mfma_gemm_bt<float><<<dim3(M_/128, 10), 256, 0, stream>>>(
        ao, wob, wob, wob, bo, bo, bo, out, out, out, E_, E_, 10);
}